// Round 6
// baseline (641.134 us; speedup 1.0000x reference)
//
#include <hip/hip_runtime.h>
#include <hip/hip_bf16.h>
#include <math.h>

#define N_NODES 100000
#define E_EDGES 3200000
#define K_HOPS  10
#define NPP     256                          // nodes per partition (dst>>8)
#define NPART   ((N_NODES + NPP - 1) / NPP)  // 391 partitions
#define CHUNK   4096                         // edges per scatter block
#define EPT     (CHUNK / 256)                // 16 edges per thread
#define NCHUNK  ((E_EDGES + CHUNK - 1) / CHUNK)   // 782 chunks
#define NFLAT   (NPART * NCHUNK)                  // 305762
#define SSEG    8192
#define GA      ((NFLAT + SSEG - 1) / SSEG)       // 38 scan blocks

typedef __attribute__((ext_vector_type(8))) short short8;
typedef __attribute__((ext_vector_type(4))) float floatx4;

__device__ __forceinline__ ushort f2bf(float f) {
    uint u = __float_as_uint(f);
    u += 0x7fffu + ((u >> 16) & 1u);
    return (ushort)(u >> 16);
}
__device__ __forceinline__ uint pk2(float a, float b) {
    return (uint)f2bf(a) | ((uint)f2bf(b) << 16);
}
__device__ __forceinline__ float bflo(uint u) { return __uint_as_float(u << 16); }
__device__ __forceinline__ float bfhi(uint u) { return __uint_as_float(u & 0xffff0000u); }

// ---------------------------------------------------------------------------
// MFMA bf16 GEMM: C = relu(A(N x KD) @ W(MD x KD)^T + bias) -> bf16 C.
// ---------------------------------------------------------------------------
template<int KD, int MD, bool A_F32>
__global__ __launch_bounds__(256) void mfma_mlp(
    const void* __restrict__ Av, const float* __restrict__ W,
    const float* __restrict__ bias, ushort* __restrict__ C)
{
    constexpr int NCT = MD / 16;
    constexpr int LDW = 88;
    __shared__ ushort Wl[MD * LDW];

    const int t    = threadIdx.x;
    const int w    = t >> 6;
    const int lane = t & 63;
    const int m    = lane & 15;
    const int quad = lane >> 4;
    const int rowBase = blockIdx.x * 128 + w * 32;

    floatx4 acc[2][NCT];
#pragma unroll
    for (int rt = 0; rt < 2; ++rt)
#pragma unroll
        for (int ct = 0; ct < NCT; ++ct) acc[rt][ct] = (floatx4)0.f;

    for (int kb = 0; kb < KD; kb += 64) {
#pragma unroll
        for (int j = 0; j < MD / 16; ++j) {
            int flat = j * 256 + t;
            int n  = flat >> 4;
            int c4 = (flat & 15) * 4;
            floatx4 v = *(const floatx4*)&W[(size_t)n * KD + kb + c4];
            *(uint2*)&Wl[n * LDW + c4] = make_uint2(pk2(v[0], v[1]), pk2(v[2], v[3]));
        }
        __syncthreads();
#pragma unroll
        for (int ks = 0; ks < 64; ks += 32) {
            short8 af[2];
#pragma unroll
            for (int rt = 0; rt < 2; ++rt) {
                int row = rowBase + rt * 16 + m;
                row = row < N_NODES ? row : N_NODES - 1;
                size_t base = (size_t)row * KD + kb + ks + quad * 8;
                if constexpr (A_F32) {
                    const float* ap = (const float*)Av + base;
                    floatx4 a0 = *(const floatx4*)ap;
                    floatx4 a1 = *(const floatx4*)(ap + 4);
                    short8 x;
                    x[0] = (short)f2bf(a0[0]); x[1] = (short)f2bf(a0[1]);
                    x[2] = (short)f2bf(a0[2]); x[3] = (short)f2bf(a0[3]);
                    x[4] = (short)f2bf(a1[0]); x[5] = (short)f2bf(a1[1]);
                    x[6] = (short)f2bf(a1[2]); x[7] = (short)f2bf(a1[3]);
                    af[rt] = x;
                } else {
                    af[rt] = *(const short8*)((const ushort*)Av + base);
                }
            }
#pragma unroll
            for (int ct = 0; ct < NCT; ++ct) {
                short8 bf = *(const short8*)&Wl[(ct * 16 + m) * LDW + ks + quad * 8];
#pragma unroll
                for (int rt = 0; rt < 2; ++rt)
                    acc[rt][ct] = __builtin_amdgcn_mfma_f32_16x16x32_bf16(
                        af[rt], bf, acc[rt][ct], 0, 0, 0);
            }
        }
        __syncthreads();
    }

#pragma unroll
    for (int rt = 0; rt < 2; ++rt) {
#pragma unroll
        for (int r = 0; r < 4; ++r) {
            int row = rowBase + rt * 16 + quad * 4 + r;
            if (row < N_NODES) {
#pragma unroll
                for (int ct = 0; ct < NCT; ++ct) {
                    int col = ct * 16 + m;
                    float v = acc[rt][ct][r] + bias[col];
                    v = v > 0.f ? v : 0.f;
                    C[(size_t)row * MD + col] = f2bf(v);
                }
            }
        }
    }
}

// ---------------------------------------------------------------------------
// CSR stage 1: per-chunk per-partition histogram -> cmat[p*NCHUNK + chunk]
// ---------------------------------------------------------------------------
__global__ __launch_bounds__(256) void hist2(
    const int* __restrict__ dst, int* __restrict__ cmat)
{
    __shared__ int lhist[NPART];
    const int t = threadIdx.x;
    for (int p = t; p < NPART; p += 256) lhist[p] = 0;
    __syncthreads();
    const int base = blockIdx.x * CHUNK;
#pragma unroll
    for (int j = 0; j < EPT; ++j) {
        int i = base + j * 256 + t;
        if (i < E_EDGES) atomicAdd(&lhist[dst[i] >> 8], 1);
    }
    __syncthreads();
    for (int p = t; p < NPART; p += 256)
        cmat[p * NCHUNK + blockIdx.x] = lhist[p];
}

// ---------------------------------------------------------------------------
// Scan level A: per-8192-segment reduction -> bsum
// ---------------------------------------------------------------------------
__global__ __launch_bounds__(1024) void scan_reduce(
    const int* __restrict__ cmat, int* __restrict__ bsum)
{
    __shared__ int wsum[16];
    const int t = threadIdx.x, lane = t & 63, wid = t >> 6;
    int base = blockIdx.x * SSEG + t * 8;
    int s = 0;
#pragma unroll
    for (int j = 0; j < 8; ++j) {
        int idx = base + j;
        if (idx < NFLAT) s += cmat[idx];
    }
#pragma unroll
    for (int d = 1; d < 64; d <<= 1) s += __shfl_xor(s, d);
    if (lane == 0) wsum[wid] = s;
    __syncthreads();
    if (t == 0) {
        int tot = 0;
#pragma unroll
        for (int i = 0; i < 16; ++i) tot += wsum[i];
        bsum[blockIdx.x] = tot;
    }
}

// ---------------------------------------------------------------------------
// Scan level B: exclusive scan of GA block sums (single wave)
// ---------------------------------------------------------------------------
__global__ void scan_tops(const int* __restrict__ bsum, int* __restrict__ boff)
{
    const int t = threadIdx.x;
    int v = (t < GA) ? bsum[t] : 0;
    int x = v;
#pragma unroll
    for (int d = 1; d < 64; d <<= 1) {
        int y = __shfl_up(x, d);
        if (t >= d) x += y;
    }
    if (t < GA) boff[t] = x - v;
}

// ---------------------------------------------------------------------------
// Scan level C: full exclusive scan applied in-place; also emits pbase[].
// ---------------------------------------------------------------------------
__global__ __launch_bounds__(1024) void scan_apply(
    int* __restrict__ cmat, const int* __restrict__ boff, int* __restrict__ pbase)
{
    __shared__ int wsum[16];
    __shared__ int woff[17];
    const int t = threadIdx.x, lane = t & 63, wid = t >> 6;
    int base = blockIdx.x * SSEG + t * 8;
    int v[8], pre[8];
    int s = 0;
#pragma unroll
    for (int j = 0; j < 8; ++j) {
        int idx = base + j;
        v[j] = (idx < NFLAT) ? cmat[idx] : 0;
        pre[j] = s;
        s += v[j];
    }
    int x = s;
#pragma unroll
    for (int d = 1; d < 64; d <<= 1) {
        int y = __shfl_up(x, d);
        if (lane >= d) x += y;
    }
    if (lane == 63) wsum[wid] = x;
    __syncthreads();
    if (wid == 0) {
        int w = (lane < 16) ? wsum[lane] : 0;
#pragma unroll
        for (int d = 1; d < 16; d <<= 1) {
            int y = __shfl_up(w, d);
            if (lane >= d) w += y;
        }
        if (lane < 16) woff[lane + 1] = w;
        if (lane == 0) woff[0] = 0;
    }
    __syncthreads();
    int tbase = boff[blockIdx.x] + woff[wid] + (x - s);
#pragma unroll
    for (int j = 0; j < 8; ++j) {
        int idx = base + j;
        if (idx < NFLAT) {
            int e = tbase + pre[j];
            cmat[idx] = e;
            if (idx % NCHUNK == 0) pbase[idx / NCHUNK] = e;
        }
    }
    if (blockIdx.x == 0 && t == 0) pbase[NPART] = E_EDGES;
}

// ---------------------------------------------------------------------------
// CSR stage 2: contention-free scatter, 8B staged entries:
//   .x = norm fp32 bits, .y = src | (dst_low8 << 17)
// Phase 1: 16 independent LDS-atomic rank chains; phase 2: 16 stores.
// ---------------------------------------------------------------------------
__global__ __launch_bounds__(256) void scatter2(
    const int* __restrict__ src, const int* __restrict__ dst,
    const float* __restrict__ ea, const int* __restrict__ cbase,
    int2* __restrict__ staging)
{
    __shared__ int lcur[NPART];
    const int t = threadIdx.x;
    const int b = blockIdx.x;
    for (int p = t; p < NPART; p += 256) lcur[p] = cbase[p * NCHUNK + b];
    __syncthreads();
    const int base = b * CHUNK;

    int d[EPT], pos[EPT];
#pragma unroll
    for (int j = 0; j < EPT; ++j) {
        int i = base + j * 256 + t;
        d[j] = (i < E_EDGES) ? dst[i] : -1;
    }
#pragma unroll
    for (int j = 0; j < EPT; ++j) {
        if (d[j] >= 0) pos[j] = atomicAdd(&lcur[d[j] >> 8], 1);
    }
#pragma unroll
    for (int j = 0; j < EPT; ++j) {
        if (d[j] >= 0) {
            int i = base + j * 256 + t;
            staging[pos[j]] = make_int2(__float_as_int(ea[i]),
                                        src[i] | ((d[j] & 255) << 17));
        }
    }
}

// ---------------------------------------------------------------------------
// CSR stage 3: one 1024-thread block per partition -> rowp + final CSR.
// ---------------------------------------------------------------------------
__global__ __launch_bounds__(1024) void partition_build(
    const int2* __restrict__ staging, const int* __restrict__ pbase,
    int* __restrict__ rowp, int2* __restrict__ csr)
{
    __shared__ int ncnt[NPP];
    __shared__ int wsum[4];
    const int p = blockIdx.x;
    const int t = threadIdx.x;
    const int e0 = pbase[p], e1 = pbase[p + 1];
    const int cnt = e1 - e0;
    const int n0 = p << 8;

    if (t < NPP) ncnt[t] = 0;
    __syncthreads();
    for (int e = t; e < cnt; e += 1024)
        atomicAdd(&ncnt[(staging[e0 + e].y >> 17) & 255], 1);
    __syncthreads();

    int x = 0, v = 0;
    if (t < NPP) {
        const int lane = t & 63, wid = t >> 6;
        v = ncnt[t];
        x = v;
#pragma unroll
        for (int d = 1; d < 64; d <<= 1) {
            int y = __shfl_up(x, d);
            if (lane >= d) x += y;
        }
        if (lane == 63) wsum[wid] = x;
    }
    __syncthreads();
    if (t < NPP) {
        const int wid = t >> 6;
        int wbase = 0;
#pragma unroll
        for (int w = 0; w < 4; ++w) if (w < wid) wbase += wsum[w];
        int excl = wbase + x - v;
        ncnt[t] = e0 + excl;
        int n = n0 + t;
        if (n < N_NODES) rowp[n] = e0 + excl;
    }
    if (p == NPART - 1 && t == 0) rowp[N_NODES] = E_EDGES;
    __syncthreads();

    for (int e = t; e < cnt; e += 1024) {
        int2 en = staging[e0 + e];
        int dlo = (en.y >> 17) & 255;
        int pos = atomicAdd(&ncnt[dlo], 1);
        csr[pos] = make_int2(en.y & 0x1FFFF, en.x);
    }
}

// ---------------------------------------------------------------------------
// k=0 combine: out = sigmoid(h.pw + pb) * h, h in bf16. 2 lanes/node.
// ---------------------------------------------------------------------------
__global__ __launch_bounds__(256) void init_out_bf16(
    const ushort* __restrict__ h, const float* __restrict__ pw,
    const float* __restrict__ pb, float* __restrict__ out)
{
    const int t = threadIdx.x;
    const int l = t & 1;
    const int n = blockIdx.x * 128 + (t >> 1);
    if (n >= N_NODES) return;
    uint4 v = *(const uint4*)&h[(size_t)n * 16 + l * 8];
    float a0 = bflo(v.x), a1 = bfhi(v.x), a2 = bflo(v.y), a3 = bfhi(v.y);
    float a4 = bflo(v.z), a5 = bfhi(v.z), a6 = bflo(v.w), a7 = bfhi(v.w);
    float4 p0 = ((const float4*)pw)[l * 2];
    float4 p1 = ((const float4*)pw)[l * 2 + 1];
    float part = a0 * p0.x + a1 * p0.y + a2 * p0.z + a3 * p0.w
               + a4 * p1.x + a5 * p1.y + a6 * p1.z + a7 * p1.w;
    part += __shfl_xor(part, 1);
    float s = 1.f / (1.f + __expf(-(part + pb[0])));
    *(float4*)&out[(size_t)n * 16 + l * 8]     = make_float4(s*a0, s*a1, s*a2, s*a3);
    *(float4*)&out[(size_t)n * 16 + l * 8 + 4] = make_float4(s*a4, s*a5, s*a6, s*a7);
}

// ---------------------------------------------------------------------------
// One hop (bf16 states) + fused combine. 8 lanes/node:
//   l = t&1 feature half, g = (t>>1)&3 edge subgroup.
// ---------------------------------------------------------------------------
__global__ __launch_bounds__(256) void hop_bf16(
    const ushort* __restrict__ prev, ushort* __restrict__ next,
    const int* __restrict__ rowp, const int2* __restrict__ csr,
    const float* __restrict__ pw, const float* __restrict__ pb,
    float* __restrict__ out)
{
    const int t = threadIdx.x;
    const int l = t & 1;
    const int g = (t >> 1) & 3;
    const int n = blockIdx.x * 32 + (t >> 3);
    if (n >= N_NODES) return;
    const int e0 = rowp[n], e1 = rowp[n + 1];
    float a[8];
#pragma unroll
    for (int j = 0; j < 8; ++j) a[j] = 0.f;

    int e = e0 + g;
    for (; e + 4 < e1; e += 8) {
        int2 c0 = csr[e];
        int2 c1 = csr[e + 4];
        float w0 = __int_as_float(c0.y);
        float w1 = __int_as_float(c1.y);
        uint4 v0 = *(const uint4*)&prev[(size_t)c0.x * 16 + l * 8];
        uint4 v1 = *(const uint4*)&prev[(size_t)c1.x * 16 + l * 8];
        a[0] += w0 * bflo(v0.x); a[1] += w0 * bfhi(v0.x);
        a[2] += w0 * bflo(v0.y); a[3] += w0 * bfhi(v0.y);
        a[4] += w0 * bflo(v0.z); a[5] += w0 * bfhi(v0.z);
        a[6] += w0 * bflo(v0.w); a[7] += w0 * bfhi(v0.w);
        a[0] += w1 * bflo(v1.x); a[1] += w1 * bfhi(v1.x);
        a[2] += w1 * bflo(v1.y); a[3] += w1 * bfhi(v1.y);
        a[4] += w1 * bflo(v1.z); a[5] += w1 * bfhi(v1.z);
        a[6] += w1 * bflo(v1.w); a[7] += w1 * bfhi(v1.w);
    }
    if (e < e1) {
        int2 c0 = csr[e];
        float w0 = __int_as_float(c0.y);
        uint4 v0 = *(const uint4*)&prev[(size_t)c0.x * 16 + l * 8];
        a[0] += w0 * bflo(v0.x); a[1] += w0 * bfhi(v0.x);
        a[2] += w0 * bflo(v0.y); a[3] += w0 * bfhi(v0.y);
        a[4] += w0 * bflo(v0.z); a[5] += w0 * bfhi(v0.z);
        a[6] += w0 * bflo(v0.w); a[7] += w0 * bfhi(v0.w);
    }

#pragma unroll
    for (int d = 2; d <= 4; d <<= 1) {
#pragma unroll
        for (int j = 0; j < 8; ++j) a[j] += __shfl_xor(a[j], d);
    }

    float4 p0 = ((const float4*)pw)[l * 2];
    float4 p1 = ((const float4*)pw)[l * 2 + 1];
    float part = a[0]*p0.x + a[1]*p0.y + a[2]*p0.z + a[3]*p0.w
               + a[4]*p1.x + a[5]*p1.y + a[6]*p1.z + a[7]*p1.w;
    part += __shfl_xor(part, 1);
    float s = 1.f / (1.f + __expf(-(part + pb[0])));

    if (g == 0) {
        uint4 nv = make_uint4(pk2(a[0], a[1]), pk2(a[2], a[3]),
                              pk2(a[4], a[5]), pk2(a[6], a[7]));
        *(uint4*)&next[(size_t)n * 16 + l * 8] = nv;
        float4 o0 = *(float4*)&out[(size_t)n * 16 + l * 8];
        float4 o1 = *(float4*)&out[(size_t)n * 16 + l * 8 + 4];
        o0.x += s*a[0]; o0.y += s*a[1]; o0.z += s*a[2]; o0.w += s*a[3];
        o1.x += s*a[4]; o1.y += s*a[5]; o1.z += s*a[6]; o1.w += s*a[7];
        *(float4*)&out[(size_t)n * 16 + l * 8]     = o0;
        *(float4*)&out[(size_t)n * 16 + l * 8 + 4] = o1;
    }
}

// ---------------------------------------------------------------------------
extern "C" void kernel_launch(void* const* d_in, const int* in_sizes, int n_in,
                              void* d_out, int out_size, void* d_ws, size_t ws_size,
                              hipStream_t stream)
{
    const float* x  = (const float*)d_in[0];
    const int*   ei = (const int*)d_in[1];
    const float* ea = (const float*)d_in[2];
    const float* w1 = (const float*)d_in[3];
    const float* b1 = (const float*)d_in[4];
    const float* w2 = (const float*)d_in[5];
    const float* b2 = (const float*)d_in[6];
    const float* w3 = (const float*)d_in[7];
    const float* b3 = (const float*)d_in[8];
    const float* pw = (const float*)d_in[9];
    const float* pb = (const float*)d_in[10];
    float* out = (float*)d_out;

    char* ws = (char*)d_ws;
    size_t off = 0;
    char*   region0 = ws + off;           off += (size_t)E_EDGES * 16;       // 51.2 MB
    ushort* pingb = (ushort*)(ws + off);  off += (size_t)N_NODES * 16 * 2;   // 3.2 MB
    ushort* pongb = (ushort*)(ws + off);  off += (size_t)N_NODES * 16 * 2;   // 3.2 MB
    int*    rowp  = (int*)(ws + off);     off += (((size_t)(N_NODES + 1) * 4) + 15) & ~(size_t)15;
    int*    cmat  = (int*)(ws + off);     off += ((size_t)NFLAT * 4 + 15) & ~(size_t)15;  // 1.22 MB
    int*    bsum  = (int*)(ws + off);     off += ((size_t)GA * 4 + 15) & ~(size_t)15;
    int*    boff  = (int*)(ws + off);     off += ((size_t)GA * 4 + 15) & ~(size_t)15;
    int*    pbase = (int*)(ws + off);     off += ((size_t)(NPART + 1) * 4 + 15) & ~(size_t)15;
    int2*   csr   = (int2*)(ws + off);    off += (size_t)E_EDGES * 8;        // 25.6 MB

    // staging (25.6MB, 8B entries) aliases h1b: CSR build completes
    // (stream-ordered) before mlp1 writes h1b.
    int2*   staging = (int2*)region0;
    ushort* h1b = (ushort*)region0;                                  // 25.6 MB
    ushort* h2b = (ushort*)(region0 + (size_t)N_NODES * 128 * 2);    // 25.6 MB

    const int* src = ei;
    const int* dst = ei + E_EDGES;

    const dim3 blk(256);
    const int mlpGrid    = (N_NODES + 127) / 128;   // 782
    const int hopGrid    = (N_NODES + 31) / 32;     // 3125

    // ---- CSR build: contention-free multi-split ----
    hist2<<<NCHUNK, blk, 0, stream>>>(dst, cmat);
    scan_reduce<<<GA, 1024, 0, stream>>>(cmat, bsum);
    scan_tops<<<1, 64, 0, stream>>>(bsum, boff);
    scan_apply<<<GA, 1024, 0, stream>>>(cmat, boff, pbase);
    scatter2<<<NCHUNK, blk, 0, stream>>>(src, dst, ea, cmat, staging);
    partition_build<<<NPART, 1024, 0, stream>>>(staging, pbase, rowp, csr);

    // ---- MLP via MFMA (bf16) ----
    mfma_mlp<256, 128, true ><<<mlpGrid, blk, 0, stream>>>(x,   w1, b1, h1b);
    mfma_mlp<128, 128, false><<<mlpGrid, blk, 0, stream>>>(h1b, w2, b2, h2b);
    mfma_mlp<128,  16, false><<<mlpGrid, blk, 0, stream>>>(h2b, w3, b3, pingb);

    // ---- k=0 combine term ----
    init_out_bf16<<<mlpGrid, blk, 0, stream>>>(pingb, pw, pb, out);

    // ---- K hops with fused combine ----
    const ushort* prev = pingb;
    ushort* next = pongb;
    for (int k = 0; k < K_HOPS; ++k) {
        hop_bf16<<<hopGrid, blk, 0, stream>>>(prev, next, rowp, csr, pw, pb, out);
        ushort* tmp = (ushort*)prev; prev = next; next = tmp;
    }
}

// Round 7
// 596.328 us; speedup vs baseline: 1.0751x; 1.0751x over previous
//
#include <hip/hip_runtime.h>
#include <hip/hip_bf16.h>
#include <math.h>

#define N_NODES 100000
#define E_EDGES 3200000
#define K_HOPS  10
#define NPP     256                          // nodes per partition (dst>>8)
#define NPART   ((N_NODES + NPP - 1) / NPP)  // 391 partitions
#define CHUNK   4096                         // edges per scatter block
#define EPT     (CHUNK / 256)                // 16 edges per thread
#define NCHUNK  ((E_EDGES + CHUNK - 1) / CHUNK)   // 782 chunks
#define NFLAT   (NPART * NCHUNK)                  // 305762
#define SSEG    8192
#define GA      ((NFLAT + SSEG - 1) / SSEG)       // 38 scan blocks

typedef __attribute__((ext_vector_type(8))) short short8;
typedef __attribute__((ext_vector_type(4))) float floatx4;

__device__ __forceinline__ ushort f2bf(float f) {
    uint u = __float_as_uint(f);
    u += 0x7fffu + ((u >> 16) & 1u);
    return (ushort)(u >> 16);
}
__device__ __forceinline__ uint pk2(float a, float b) {
    return (uint)f2bf(a) | ((uint)f2bf(b) << 16);
}
__device__ __forceinline__ float bflo(uint u) { return __uint_as_float(u << 16); }
__device__ __forceinline__ float bfhi(uint u) { return __uint_as_float(u & 0xffff0000u); }

// ---------------------------------------------------------------------------
// MFMA bf16 GEMM: C = relu(A(N x KD) @ W(MD x KD)^T + bias) -> bf16 C.
// ---------------------------------------------------------------------------
template<int KD, int MD, bool A_F32>
__global__ __launch_bounds__(256) void mfma_mlp(
    const void* __restrict__ Av, const float* __restrict__ W,
    const float* __restrict__ bias, ushort* __restrict__ C)
{
    constexpr int NCT = MD / 16;
    constexpr int LDW = 88;
    __shared__ ushort Wl[MD * LDW];

    const int t    = threadIdx.x;
    const int w    = t >> 6;
    const int lane = t & 63;
    const int m    = lane & 15;
    const int quad = lane >> 4;
    const int rowBase = blockIdx.x * 128 + w * 32;

    floatx4 acc[2][NCT];
#pragma unroll
    for (int rt = 0; rt < 2; ++rt)
#pragma unroll
        for (int ct = 0; ct < NCT; ++ct) acc[rt][ct] = (floatx4)0.f;

    for (int kb = 0; kb < KD; kb += 64) {
#pragma unroll
        for (int j = 0; j < MD / 16; ++j) {
            int flat = j * 256 + t;
            int n  = flat >> 4;
            int c4 = (flat & 15) * 4;
            floatx4 v = *(const floatx4*)&W[(size_t)n * KD + kb + c4];
            *(uint2*)&Wl[n * LDW + c4] = make_uint2(pk2(v[0], v[1]), pk2(v[2], v[3]));
        }
        __syncthreads();
#pragma unroll
        for (int ks = 0; ks < 64; ks += 32) {
            short8 af[2];
#pragma unroll
            for (int rt = 0; rt < 2; ++rt) {
                int row = rowBase + rt * 16 + m;
                row = row < N_NODES ? row : N_NODES - 1;
                size_t base = (size_t)row * KD + kb + ks + quad * 8;
                if constexpr (A_F32) {
                    const float* ap = (const float*)Av + base;
                    floatx4 a0 = *(const floatx4*)ap;
                    floatx4 a1 = *(const floatx4*)(ap + 4);
                    short8 x;
                    x[0] = (short)f2bf(a0[0]); x[1] = (short)f2bf(a0[1]);
                    x[2] = (short)f2bf(a0[2]); x[3] = (short)f2bf(a0[3]);
                    x[4] = (short)f2bf(a1[0]); x[5] = (short)f2bf(a1[1]);
                    x[6] = (short)f2bf(a1[2]); x[7] = (short)f2bf(a1[3]);
                    af[rt] = x;
                } else {
                    af[rt] = *(const short8*)((const ushort*)Av + base);
                }
            }
#pragma unroll
            for (int ct = 0; ct < NCT; ++ct) {
                short8 bf = *(const short8*)&Wl[(ct * 16 + m) * LDW + ks + quad * 8];
#pragma unroll
                for (int rt = 0; rt < 2; ++rt)
                    acc[rt][ct] = __builtin_amdgcn_mfma_f32_16x16x32_bf16(
                        af[rt], bf, acc[rt][ct], 0, 0, 0);
            }
        }
        __syncthreads();
    }

#pragma unroll
    for (int rt = 0; rt < 2; ++rt) {
#pragma unroll
        for (int r = 0; r < 4; ++r) {
            int row = rowBase + rt * 16 + quad * 4 + r;
            if (row < N_NODES) {
#pragma unroll
                for (int ct = 0; ct < NCT; ++ct) {
                    int col = ct * 16 + m;
                    float v = acc[rt][ct][r] + bias[col];
                    v = v > 0.f ? v : 0.f;
                    C[(size_t)row * MD + col] = f2bf(v);
                }
            }
        }
    }
}

// ---------------------------------------------------------------------------
// CSR stage 1: per-chunk per-partition histogram -> cmat[p*NCHUNK + chunk]
// ---------------------------------------------------------------------------
__global__ __launch_bounds__(256) void hist2(
    const int* __restrict__ dst, int* __restrict__ cmat)
{
    __shared__ int lhist[NPART];
    const int t = threadIdx.x;
    for (int p = t; p < NPART; p += 256) lhist[p] = 0;
    __syncthreads();
    const int base = blockIdx.x * CHUNK;
#pragma unroll
    for (int j = 0; j < EPT; ++j) {
        int i = base + j * 256 + t;
        if (i < E_EDGES) atomicAdd(&lhist[dst[i] >> 8], 1);
    }
    __syncthreads();
    for (int p = t; p < NPART; p += 256)
        cmat[p * NCHUNK + blockIdx.x] = lhist[p];
}

// ---------------------------------------------------------------------------
// Scan level A: per-8192-segment reduction -> bsum
// ---------------------------------------------------------------------------
__global__ __launch_bounds__(1024) void scan_reduce(
    const int* __restrict__ cmat, int* __restrict__ bsum)
{
    __shared__ int wsum[16];
    const int t = threadIdx.x, lane = t & 63, wid = t >> 6;
    int base = blockIdx.x * SSEG + t * 8;
    int s = 0;
#pragma unroll
    for (int j = 0; j < 8; ++j) {
        int idx = base + j;
        if (idx < NFLAT) s += cmat[idx];
    }
#pragma unroll
    for (int d = 1; d < 64; d <<= 1) s += __shfl_xor(s, d);
    if (lane == 0) wsum[wid] = s;
    __syncthreads();
    if (t == 0) {
        int tot = 0;
#pragma unroll
        for (int i = 0; i < 16; ++i) tot += wsum[i];
        bsum[blockIdx.x] = tot;
    }
}

// ---------------------------------------------------------------------------
// Scan level B: exclusive scan of GA block sums (single wave)
// ---------------------------------------------------------------------------
__global__ void scan_tops(const int* __restrict__ bsum, int* __restrict__ boff)
{
    const int t = threadIdx.x;
    int v = (t < GA) ? bsum[t] : 0;
    int x = v;
#pragma unroll
    for (int d = 1; d < 64; d <<= 1) {
        int y = __shfl_up(x, d);
        if (t >= d) x += y;
    }
    if (t < GA) boff[t] = x - v;
}

// ---------------------------------------------------------------------------
// Scan level C: full exclusive scan applied in-place; also emits pbase[].
// ---------------------------------------------------------------------------
__global__ __launch_bounds__(1024) void scan_apply(
    int* __restrict__ cmat, const int* __restrict__ boff, int* __restrict__ pbase)
{
    __shared__ int wsum[16];
    __shared__ int woff[17];
    const int t = threadIdx.x, lane = t & 63, wid = t >> 6;
    int base = blockIdx.x * SSEG + t * 8;
    int v[8], pre[8];
    int s = 0;
#pragma unroll
    for (int j = 0; j < 8; ++j) {
        int idx = base + j;
        v[j] = (idx < NFLAT) ? cmat[idx] : 0;
        pre[j] = s;
        s += v[j];
    }
    int x = s;
#pragma unroll
    for (int d = 1; d < 64; d <<= 1) {
        int y = __shfl_up(x, d);
        if (lane >= d) x += y;
    }
    if (lane == 63) wsum[wid] = x;
    __syncthreads();
    if (wid == 0) {
        int w = (lane < 16) ? wsum[lane] : 0;
#pragma unroll
        for (int d = 1; d < 16; d <<= 1) {
            int y = __shfl_up(w, d);
            if (lane >= d) w += y;
        }
        if (lane < 16) woff[lane + 1] = w;
        if (lane == 0) woff[0] = 0;
    }
    __syncthreads();
    int tbase = boff[blockIdx.x] + woff[wid] + (x - s);
#pragma unroll
    for (int j = 0; j < 8; ++j) {
        int idx = base + j;
        if (idx < NFLAT) {
            int e = tbase + pre[j];
            cmat[idx] = e;
            if (idx % NCHUNK == 0) pbase[idx / NCHUNK] = e;
        }
    }
    if (blockIdx.x == 0 && t == 0) pbase[NPART] = E_EDGES;
}

// ---------------------------------------------------------------------------
// CSR stage 2: LDS-sorted scatter. Edges are binned by partition inside LDS,
// then streamed out in sorted order so consecutive lanes write consecutive
// global addresses within each run (HW-coalesced full-line stores).
// Entry: .x = norm fp32 bits, .y = src | (dst_low8 << 17)
// ---------------------------------------------------------------------------
__global__ __launch_bounds__(256) void scatter3(
    const int* __restrict__ src, const int* __restrict__ dst,
    const float* __restrict__ ea, const int* __restrict__ cbase,
    int2* __restrict__ staging)
{
    __shared__ int2 ebuf[CHUNK];     // 32 KB sorted entries
    __shared__ int  gaddr[CHUNK];    // 16 KB global positions
    __shared__ int  lcnt[NPART];     // counts -> cursors (local sorted idx)
    __shared__ int  goff[NPART];     // global pos = goff[p] + local idx
    __shared__ int  wsum[4];
    const int t = threadIdx.x;
    const int b = blockIdx.x;
    const int base = b * CHUNK;
    const int cnt = min(CHUNK, E_EDGES - base);
    const int lane = t & 63, wid = t >> 6;

    for (int p = t; p < NPART; p += 256) lcnt[p] = 0;
    __syncthreads();

    int d[EPT];
#pragma unroll
    for (int j = 0; j < EPT; ++j) {
        int i = base + j * 256 + t;
        d[j] = (i < E_EDGES) ? dst[i] : -1;
        if (d[j] >= 0) atomicAdd(&lcnt[d[j] >> 8], 1);
    }
    __syncthreads();

    // exclusive scan of NPART counts, 2 per thread
    int v0 = (2 * t     < NPART) ? lcnt[2 * t]     : 0;
    int v1 = (2 * t + 1 < NPART) ? lcnt[2 * t + 1] : 0;
    int pair = v0 + v1;
    int x = pair;
#pragma unroll
    for (int dd = 1; dd < 64; dd <<= 1) {
        int y = __shfl_up(x, dd);
        if (lane >= dd) x += y;
    }
    if (lane == 63) wsum[wid] = x;
    __syncthreads();
    int wbase = 0;
#pragma unroll
    for (int w = 0; w < 4; ++w) if (w < wid) wbase += wsum[w];
    int excl = wbase + x - pair;
    if (2 * t < NPART) {
        lcnt[2 * t] = excl;
        goff[2 * t] = cbase[(2 * t) * NCHUNK + b] - excl;
    }
    if (2 * t + 1 < NPART) {
        lcnt[2 * t + 1] = excl + v0;
        goff[2 * t + 1] = cbase[(2 * t + 1) * NCHUNK + b] - (excl + v0);
    }
    __syncthreads();

    // place into LDS sorted by partition
#pragma unroll
    for (int j = 0; j < EPT; ++j) {
        if (d[j] >= 0) {
            int i = base + j * 256 + t;
            int p = d[j] >> 8;
            int s = atomicAdd(&lcnt[p], 1);
            ebuf[s]  = make_int2(__float_as_int(ea[i]),
                                 src[i] | ((d[j] & 255) << 17));
            gaddr[s] = goff[p] + s;
        }
    }
    __syncthreads();

    // stream out in sorted order: coalesced within runs
    for (int k = t; k < cnt; k += 256)
        staging[gaddr[k]] = ebuf[k];
}

// ---------------------------------------------------------------------------
// CSR stage 3: one 1024-thread block per partition -> rowp + final CSR.
// ---------------------------------------------------------------------------
__global__ __launch_bounds__(1024) void partition_build(
    const int2* __restrict__ staging, const int* __restrict__ pbase,
    int* __restrict__ rowp, int2* __restrict__ csr)
{
    __shared__ int ncnt[NPP];
    __shared__ int wsum[4];
    const int p = blockIdx.x;
    const int t = threadIdx.x;
    const int e0 = pbase[p], e1 = pbase[p + 1];
    const int cnt = e1 - e0;
    const int n0 = p << 8;

    if (t < NPP) ncnt[t] = 0;
    __syncthreads();
    for (int e = t; e < cnt; e += 1024)
        atomicAdd(&ncnt[(staging[e0 + e].y >> 17) & 255], 1);
    __syncthreads();

    int x = 0, v = 0;
    if (t < NPP) {
        const int lane = t & 63, wid = t >> 6;
        v = ncnt[t];
        x = v;
#pragma unroll
        for (int d = 1; d < 64; d <<= 1) {
            int y = __shfl_up(x, d);
            if (lane >= d) x += y;
        }
        if (lane == 63) wsum[wid] = x;
    }
    __syncthreads();
    if (t < NPP) {
        const int wid = t >> 6;
        int wbase = 0;
#pragma unroll
        for (int w = 0; w < 4; ++w) if (w < wid) wbase += wsum[w];
        int excl = wbase + x - v;
        ncnt[t] = e0 + excl;
        int n = n0 + t;
        if (n < N_NODES) rowp[n] = e0 + excl;
    }
    if (p == NPART - 1 && t == 0) rowp[N_NODES] = E_EDGES;
    __syncthreads();

    for (int e = t; e < cnt; e += 1024) {
        int2 en = staging[e0 + e];
        int dlo = (en.y >> 17) & 255;
        int pos = atomicAdd(&ncnt[dlo], 1);
        csr[pos] = make_int2(en.y & 0x1FFFF, en.x);
    }
}

// ---------------------------------------------------------------------------
// k=0 combine: out = sigmoid(h.pw + pb) * h, h in bf16. 2 lanes/node.
// ---------------------------------------------------------------------------
__global__ __launch_bounds__(256) void init_out_bf16(
    const ushort* __restrict__ h, const float* __restrict__ pw,
    const float* __restrict__ pb, float* __restrict__ out)
{
    const int t = threadIdx.x;
    const int l = t & 1;
    const int n = blockIdx.x * 128 + (t >> 1);
    if (n >= N_NODES) return;
    uint4 v = *(const uint4*)&h[(size_t)n * 16 + l * 8];
    float a0 = bflo(v.x), a1 = bfhi(v.x), a2 = bflo(v.y), a3 = bfhi(v.y);
    float a4 = bflo(v.z), a5 = bfhi(v.z), a6 = bflo(v.w), a7 = bfhi(v.w);
    float4 p0 = ((const float4*)pw)[l * 2];
    float4 p1 = ((const float4*)pw)[l * 2 + 1];
    float part = a0 * p0.x + a1 * p0.y + a2 * p0.z + a3 * p0.w
               + a4 * p1.x + a5 * p1.y + a6 * p1.z + a7 * p1.w;
    part += __shfl_xor(part, 1);
    float s = 1.f / (1.f + __expf(-(part + pb[0])));
    *(float4*)&out[(size_t)n * 16 + l * 8]     = make_float4(s*a0, s*a1, s*a2, s*a3);
    *(float4*)&out[(size_t)n * 16 + l * 8 + 4] = make_float4(s*a4, s*a5, s*a6, s*a7);
}

// ---------------------------------------------------------------------------
// One hop (bf16 states) + fused combine. 8 lanes/node, 4 gathers in flight.
// ---------------------------------------------------------------------------
__global__ __launch_bounds__(256) void hop_bf16(
    const ushort* __restrict__ prev, ushort* __restrict__ next,
    const int* __restrict__ rowp, const int2* __restrict__ csr,
    const float* __restrict__ pw, const float* __restrict__ pb,
    float* __restrict__ out)
{
    const int t = threadIdx.x;
    const int l = t & 1;
    const int g = (t >> 1) & 3;
    const int n = blockIdx.x * 32 + (t >> 3);
    if (n >= N_NODES) return;
    const int e0 = rowp[n], e1 = rowp[n + 1];
    float a[8];
#pragma unroll
    for (int j = 0; j < 8; ++j) a[j] = 0.f;

    int e = e0 + g;
    for (; e + 12 < e1; e += 16) {
        int2 c0 = csr[e];
        int2 c1 = csr[e + 4];
        int2 c2 = csr[e + 8];
        int2 c3 = csr[e + 12];
        float w0 = __int_as_float(c0.y), w1 = __int_as_float(c1.y);
        float w2 = __int_as_float(c2.y), w3 = __int_as_float(c3.y);
        uint4 v0 = *(const uint4*)&prev[(size_t)c0.x * 16 + l * 8];
        uint4 v1 = *(const uint4*)&prev[(size_t)c1.x * 16 + l * 8];
        uint4 v2 = *(const uint4*)&prev[(size_t)c2.x * 16 + l * 8];
        uint4 v3 = *(const uint4*)&prev[(size_t)c3.x * 16 + l * 8];
        a[0] += w0 * bflo(v0.x); a[1] += w0 * bfhi(v0.x);
        a[2] += w0 * bflo(v0.y); a[3] += w0 * bfhi(v0.y);
        a[4] += w0 * bflo(v0.z); a[5] += w0 * bfhi(v0.z);
        a[6] += w0 * bflo(v0.w); a[7] += w0 * bfhi(v0.w);
        a[0] += w1 * bflo(v1.x); a[1] += w1 * bfhi(v1.x);
        a[2] += w1 * bflo(v1.y); a[3] += w1 * bfhi(v1.y);
        a[4] += w1 * bflo(v1.z); a[5] += w1 * bfhi(v1.z);
        a[6] += w1 * bflo(v1.w); a[7] += w1 * bfhi(v1.w);
        a[0] += w2 * bflo(v2.x); a[1] += w2 * bfhi(v2.x);
        a[2] += w2 * bflo(v2.y); a[3] += w2 * bfhi(v2.y);
        a[4] += w2 * bflo(v2.z); a[5] += w2 * bfhi(v2.z);
        a[6] += w2 * bflo(v2.w); a[7] += w2 * bfhi(v2.w);
        a[0] += w3 * bflo(v3.x); a[1] += w3 * bfhi(v3.x);
        a[2] += w3 * bflo(v3.y); a[3] += w3 * bfhi(v3.y);
        a[4] += w3 * bflo(v3.z); a[5] += w3 * bfhi(v3.z);
        a[6] += w3 * bflo(v3.w); a[7] += w3 * bfhi(v3.w);
    }
    for (; e < e1; e += 4) {
        int2 c0 = csr[e];
        float w0 = __int_as_float(c0.y);
        uint4 v0 = *(const uint4*)&prev[(size_t)c0.x * 16 + l * 8];
        a[0] += w0 * bflo(v0.x); a[1] += w0 * bfhi(v0.x);
        a[2] += w0 * bflo(v0.y); a[3] += w0 * bfhi(v0.y);
        a[4] += w0 * bflo(v0.z); a[5] += w0 * bfhi(v0.z);
        a[6] += w0 * bflo(v0.w); a[7] += w0 * bfhi(v0.w);
    }

#pragma unroll
    for (int d = 2; d <= 4; d <<= 1) {
#pragma unroll
        for (int j = 0; j < 8; ++j) a[j] += __shfl_xor(a[j], d);
    }

    float4 p0 = ((const float4*)pw)[l * 2];
    float4 p1 = ((const float4*)pw)[l * 2 + 1];
    float part = a[0]*p0.x + a[1]*p0.y + a[2]*p0.z + a[3]*p0.w
               + a[4]*p1.x + a[5]*p1.y + a[6]*p1.z + a[7]*p1.w;
    part += __shfl_xor(part, 1);
    float s = 1.f / (1.f + __expf(-(part + pb[0])));

    if (g == 0) {
        uint4 nv = make_uint4(pk2(a[0], a[1]), pk2(a[2], a[3]),
                              pk2(a[4], a[5]), pk2(a[6], a[7]));
        *(uint4*)&next[(size_t)n * 16 + l * 8] = nv;
        float4 o0 = *(float4*)&out[(size_t)n * 16 + l * 8];
        float4 o1 = *(float4*)&out[(size_t)n * 16 + l * 8 + 4];
        o0.x += s*a[0]; o0.y += s*a[1]; o0.z += s*a[2]; o0.w += s*a[3];
        o1.x += s*a[4]; o1.y += s*a[5]; o1.z += s*a[6]; o1.w += s*a[7];
        *(float4*)&out[(size_t)n * 16 + l * 8]     = o0;
        *(float4*)&out[(size_t)n * 16 + l * 8 + 4] = o1;
    }
}

// ---------------------------------------------------------------------------
extern "C" void kernel_launch(void* const* d_in, const int* in_sizes, int n_in,
                              void* d_out, int out_size, void* d_ws, size_t ws_size,
                              hipStream_t stream)
{
    const float* x  = (const float*)d_in[0];
    const int*   ei = (const int*)d_in[1];
    const float* ea = (const float*)d_in[2];
    const float* w1 = (const float*)d_in[3];
    const float* b1 = (const float*)d_in[4];
    const float* w2 = (const float*)d_in[5];
    const float* b2 = (const float*)d_in[6];
    const float* w3 = (const float*)d_in[7];
    const float* b3 = (const float*)d_in[8];
    const float* pw = (const float*)d_in[9];
    const float* pb = (const float*)d_in[10];
    float* out = (float*)d_out;

    char* ws = (char*)d_ws;
    size_t off = 0;
    char*   region0 = ws + off;           off += (size_t)E_EDGES * 16;       // 51.2 MB
    ushort* pingb = (ushort*)(ws + off);  off += (size_t)N_NODES * 16 * 2;   // 3.2 MB
    ushort* pongb = (ushort*)(ws + off);  off += (size_t)N_NODES * 16 * 2;   // 3.2 MB
    int*    rowp  = (int*)(ws + off);     off += (((size_t)(N_NODES + 1) * 4) + 15) & ~(size_t)15;
    int*    cmat  = (int*)(ws + off);     off += ((size_t)NFLAT * 4 + 15) & ~(size_t)15;  // 1.22 MB
    int*    bsum  = (int*)(ws + off);     off += ((size_t)GA * 4 + 15) & ~(size_t)15;
    int*    boff  = (int*)(ws + off);     off += ((size_t)GA * 4 + 15) & ~(size_t)15;
    int*    pbase = (int*)(ws + off);     off += ((size_t)(NPART + 1) * 4 + 15) & ~(size_t)15;
    int2*   csr   = (int2*)(ws + off);    off += (size_t)E_EDGES * 8;        // 25.6 MB

    // staging (25.6MB, 8B entries) aliases h1b: CSR build completes
    // (stream-ordered) before mlp1 writes h1b.
    int2*   staging = (int2*)region0;
    ushort* h1b = (ushort*)region0;                                  // 25.6 MB
    ushort* h2b = (ushort*)(region0 + (size_t)N_NODES * 128 * 2);    // 25.6 MB

    const int* src = ei;
    const int* dst = ei + E_EDGES;

    const dim3 blk(256);
    const int mlpGrid    = (N_NODES + 127) / 128;   // 782
    const int hopGrid    = (N_NODES + 31) / 32;     // 3125

    // ---- CSR build: contention-free multi-split ----
    hist2<<<NCHUNK, blk, 0, stream>>>(dst, cmat);
    scan_reduce<<<GA, 1024, 0, stream>>>(cmat, bsum);
    scan_tops<<<1, 64, 0, stream>>>(bsum, boff);
    scan_apply<<<GA, 1024, 0, stream>>>(cmat, boff, pbase);
    scatter3<<<NCHUNK, blk, 0, stream>>>(src, dst, ea, cmat, staging);
    partition_build<<<NPART, 1024, 0, stream>>>(staging, pbase, rowp, csr);

    // ---- MLP via MFMA (bf16) ----
    mfma_mlp<256, 128, true ><<<mlpGrid, blk, 0, stream>>>(x,   w1, b1, h1b);
    mfma_mlp<128, 128, false><<<mlpGrid, blk, 0, stream>>>(h1b, w2, b2, h2b);
    mfma_mlp<128,  16, false><<<mlpGrid, blk, 0, stream>>>(h2b, w3, b3, pingb);

    // ---- k=0 combine term ----
    init_out_bf16<<<mlpGrid, blk, 0, stream>>>(pingb, pw, pb, out);

    // ---- K hops with fused combine ----
    const ushort* prev = pingb;
    ushort* next = pongb;
    for (int k = 0; k < K_HOPS; ++k) {
        hop_bf16<<<hopGrid, blk, 0, stream>>>(prev, next, rowp, csr, pw, pb, out);
        ushort* tmp = (ushort*)prev; prev = next; next = tmp;
    }
}